// Round 11
// baseline (465.375 us; speedup 1.0000x reference)
//
#include <hip/hip_runtime.h>
#include <hip/hip_bf16.h>
#include <hip/hip_fp8.h>

#define NN 50000
#define NE 1600000
#define FIN 128
#define HH 256
#define GG 64
#define AA 16
#define NB ((NN + 255) / 256)   // 196 scan blocks
#define NRANGE 8
#define RSZ (NN / NRANGE)        // 6250 dst nodes per XCD range

typedef __attribute__((ext_vector_type(8))) short short8;
typedef __attribute__((ext_vector_type(4))) float f32x4;
typedef __attribute__((ext_vector_type(4))) int   i32x4;   // native vec for nt builtins
typedef __attribute__((ext_vector_type(4))) uint  u32x4;

static __device__ __forceinline__ ushort f2b(float f) {
    union { __hip_bfloat16 h; ushort u; } v; v.h = __float2bfloat16(f); return v.u;
}
static __device__ __forceinline__ float b2f_lo(uint a) {
    union { float f; uint u; } v; v.u = a << 16; return v.f;
}
template<int SEL>
static __device__ __forceinline__ float f8tof(uint u) {
#if __has_builtin(__builtin_amdgcn_cvt_f32_fp8)
    return __builtin_amdgcn_cvt_f32_fp8(u, SEL);
#else
    union { unsigned char c; __hip_fp8_e4m3 f; } v;
    v.c = (u >> (SEL * 8)) & 0xFF;
    return (float)v.f;
#endif
}
static __device__ __forceinline__ unsigned char ftof8(float f) {
    __hip_fp8_e4m3 v(f);
    return *reinterpret_cast<unsigned char*>(&v);
}

// ---------------- merged prep: casts + zero-init ----------------
__global__ void k_prep(const float* __restrict__ x, ushort* __restrict__ xb,
                       unsigned char* __restrict__ xf8,
                       const float* __restrict__ Wl1, const float* __restrict__ Wr1,
                       ushort* __restrict__ Wt1,
                       const float* __restrict__ Wl2, const float* __restrict__ Wr2,
                       ushort* __restrict__ Wt2,
                       int* __restrict__ degi, float* __restrict__ gz) {
    int b = blockIdx.x, t = threadIdx.x;
    if (b < 6250) {
        int i = b * 256 + t;                               // exact: NN*FIN/4
        float4 v = reinterpret_cast<const float4*>(x)[i];
        ushort4 o; o.x = f2b(v.x); o.y = f2b(v.y); o.z = f2b(v.z); o.w = f2b(v.w);
        reinterpret_cast<ushort4*>(xb)[i] = o;
        uchar4 p; p.x = ftof8(v.x); p.y = ftof8(v.y); p.z = ftof8(v.z); p.w = ftof8(v.w);
        reinterpret_cast<uchar4*>(xf8)[i] = p;
    } else if (b < 6506) {
        int i = (b - 6250) * 256 + t;                      // exact: 256*256
        int n = i / 256, k = i % 256;
        float v = (k < 128) ? Wl1[k * HH + n] : Wr1[(k - 128) * HH + n];
        Wt1[i] = f2b(v);
    } else if (b < 7018) {
        int i = (b - 6506) * 256 + t;                      // exact: 256*512
        int n = i / 512, k = i % 512;
        float v = (k < 256) ? Wl2[k * HH + n] : Wr2[(k - 256) * HH + n];
        Wt2[i] = f2b(v);
    } else if (b < 7214) {
        int i = (b - 7018) * 256 + t;
        if (i < NN) degi[i] = 0;
    } else {
        int i = (b - 7214) * 256 + t;
        if (i < GG + GG * HH) gz[i] = 0.0f;
    }
}

// ---------------- degree histogram, XCD-partitioned, nt streaming reads ----------
__global__ void k_degi(const int* __restrict__ dst, int* __restrict__ degi) {
    int range = blockIdx.x & 7;
    int i = (blockIdx.x >> 3) * 256 + threadIdx.x;
    if (i >= NE / 4) return;
    i32x4 d = __builtin_nontemporal_load(reinterpret_cast<const i32x4*>(dst) + i);
    int lo = range * RSZ, hi = lo + RSZ;
    if (d.x >= lo && d.x < hi) atomicAdd(&degi[d.x], 1);
    if (d.y >= lo && d.y < hi) atomicAdd(&degi[d.y], 1);
    if (d.z >= lo && d.z < hi) atomicAdd(&degi[d.z], 1);
    if (d.w >= lo && d.w < hi) atomicAdd(&degi[d.w], 1);
}

__global__ void k_gdeg(const int* __restrict__ batch, float* __restrict__ gcnt) {
    __shared__ float h[GG];
    int t = threadIdx.x;
    if (t < GG) h[t] = 0.0f;
    __syncthreads();
    int i = blockIdx.x * 256 + t;
    if (i < NN) atomicAdd(&h[batch[i]], 1.0f);
    __syncthreads();
    if (t < GG && h[t] != 0.0f) atomicAdd(&gcnt[t], h[t]);
}

// ---------------- prefix sum over degrees ----------------
__global__ void k_scan1(const int* __restrict__ degi, int* __restrict__ blocksum) {
    __shared__ int s[256];
    int t = threadIdx.x, i = blockIdx.x * 256 + t;
    s[t] = i < NN ? degi[i] : 0;
    __syncthreads();
    for (int d = 128; d > 0; d >>= 1) { if (t < d) s[t] += s[t + d]; __syncthreads(); }
    if (t == 0) blocksum[blockIdx.x] = s[0];
}

__global__ void k_scan2(const int* __restrict__ blocksum, int* __restrict__ blockoff) {
    __shared__ int s[256];
    int t = threadIdx.x;
    int v = t < NB ? blocksum[t] : 0;
    s[t] = v; __syncthreads();
    for (int d = 1; d < 256; d <<= 1) {
        int x = t >= d ? s[t - d] : 0; __syncthreads();
        s[t] += x; __syncthreads();
    }
    if (t < NB) blockoff[t] = s[t] - v;
}

__global__ void k_scan3(const int* __restrict__ degi, const int* __restrict__ blockoff,
                        int* __restrict__ offsets, int* __restrict__ cursor) {
    __shared__ int s[256];
    int t = threadIdx.x, i = blockIdx.x * 256 + t;
    int v = i < NN ? degi[i] : 0;
    s[t] = v; __syncthreads();
    for (int d = 1; d < 256; d <<= 1) {
        int x = t >= d ? s[t - d] : 0; __syncthreads();
        s[t] += x; __syncthreads();
    }
    if (i < NN) {
        int off = blockoff[blockIdx.x] + s[t] - v;
        offsets[i] = off;
        cursor[i]  = off;
    }
    if (i == 0) offsets[NN] = NE;
}

// ---------------- CSR fill, XCD-partitioned, nt streaming reads ----------------
__global__ void k_fill(const int* __restrict__ src, const int* __restrict__ dst,
                       int* __restrict__ cursor, int* __restrict__ csr_src) {
    int range = blockIdx.x & 7;
    int i = (blockIdx.x >> 3) * 256 + threadIdx.x;
    if (i >= NE / 4) return;
    i32x4 d = __builtin_nontemporal_load(reinterpret_cast<const i32x4*>(dst) + i);
    i32x4 s = __builtin_nontemporal_load(reinterpret_cast<const i32x4*>(src) + i);
    int lo = range * RSZ, hi = lo + RSZ;
    if (d.x >= lo && d.x < hi) csr_src[atomicAdd(&cursor[d.x], 1)] = s.x;
    if (d.y >= lo && d.y < hi) csr_src[atomicAdd(&cursor[d.y], 1)] = s.y;
    if (d.z >= lo && d.z < hi) csr_src[atomicAdd(&cursor[d.z], 1)] = s.z;
    if (d.w >= lo && d.w < hi) csr_src[atomicAdd(&cursor[d.w], 1)] = s.w;
}

// ---------------- XCD-sliced gather mean-aggregation (fp8 table -> bf16) -------
// Column slice of 64 fp8 (64 B, granule-aligned) owned by a fixed XCD group:
//   C=256: 4 slices x 2 XCDs (25k nodes each)  -> per-XCD working set 3.2 MB (L2-fit)
//   C=128: 2 slices x 4 XCDs (12.5k nodes each)-> per-XCD working set 3.2 MB (L2-fit)
// blockIdx%8 -> XCD (round-robin heuristic). 16-lane subgroup per node; lane
// reads 1 dword (4 fp8) per edge. Per-column sum order identical to before.
template<int C>
__global__ void __launch_bounds__(256) k_gather_xcd(
        const int* __restrict__ offsets, const int* __restrict__ csr_src,
        const unsigned char* __restrict__ feat, ushort* __restrict__ agg) {
    constexpr int NSLICE = C / 64;          // 2 or 4
    constexpr int XPS    = 8 / NSLICE;      // XCDs per slice
    constexpr int NPS    = NN / XPS;        // nodes per XCD sub-range
    const int xcd   = blockIdx.x & 7;
    const int chunk = blockIdx.x >> 3;
    int slice, sub;
    if constexpr (NSLICE == 4) { slice = xcd >> 1; sub = xcd & 1; }
    else                       { slice = xcd >> 2; sub = xcd & 3; }
    const int sg = threadIdx.x >> 4;        // subgroup 0..15
    const int ln = threadIdx.x & 15;
    const int loc = chunk * 16 + sg;
    if (loc >= NPS) return;
    const int node = sub * NPS + loc;
    const int o0 = offsets[node], o1 = offsets[node + 1];
    const unsigned char* fp = feat + slice * 64 + ln * 4;

    float a0 = 0.f, a1 = 0.f, a2 = 0.f, a3 = 0.f;
    int t = o0;
    for (; t + 3 < o1; t += 4) {
        int s0 = __builtin_nontemporal_load(csr_src + t);
        int s1 = __builtin_nontemporal_load(csr_src + t + 1);
        int s2 = __builtin_nontemporal_load(csr_src + t + 2);
        int s3 = __builtin_nontemporal_load(csr_src + t + 3);
        uint u0 = *(const uint*)(fp + (size_t)s0 * C);
        uint u1 = *(const uint*)(fp + (size_t)s1 * C);
        uint u2 = *(const uint*)(fp + (size_t)s2 * C);
        uint u3 = *(const uint*)(fp + (size_t)s3 * C);
        a0 += (f8tof<0>(u0) + f8tof<0>(u1)) + (f8tof<0>(u2) + f8tof<0>(u3));
        a1 += (f8tof<1>(u0) + f8tof<1>(u1)) + (f8tof<1>(u2) + f8tof<1>(u3));
        a2 += (f8tof<2>(u0) + f8tof<2>(u1)) + (f8tof<2>(u2) + f8tof<2>(u3));
        a3 += (f8tof<3>(u0) + f8tof<3>(u1)) + (f8tof<3>(u2) + f8tof<3>(u3));
    }
    for (; t < o1; ++t) {
        int s0 = __builtin_nontemporal_load(csr_src + t);
        uint u0 = *(const uint*)(fp + (size_t)s0 * C);
        a0 += f8tof<0>(u0); a1 += f8tof<1>(u0);
        a2 += f8tof<2>(u0); a3 += f8tof<3>(u0);
    }

    int deg = o1 - o0;
    float r = __builtin_amdgcn_rcpf(deg > 1 ? (float)deg : 1.0f);
    uint2 o;
    o.x = (uint)f2b(a0 * r) | ((uint)f2b(a1 * r) << 16);
    o.y = (uint)f2b(a2 * r) | ((uint)f2b(a3 * r) << 16);
    *(uint2*)(agg + (size_t)node * C + slice * 64 + ln * 4) = o;
}

// ---------------- SAGE layer via MFMA: 128 nodes x 256 cols per block ----------
template<int K>
__global__ void __launch_bounds__(256) k_sage_mfma(
        const ushort* __restrict__ agg, const ushort* __restrict__ xin,
        const ushort* __restrict__ Wt, const float* __restrict__ bias,
        ushort* __restrict__ outb, unsigned char* __restrict__ out8) {
    constexpr int KH = K / 2;
    constexpr int LDP = 40;                    // padded row stride (shorts)
    __shared__ ushort As[128 * LDP];           // 128 nodes x 32 k
    __shared__ ushort Bs[256 * LDP];           // 256 cols x 32 k

    const int tid  = threadIdx.x;
    const int lane = tid & 63;
    const int w    = tid >> 6;
    const int base = blockIdx.x * 128;
    const int r    = lane & 15;
    const int kh   = lane >> 4;                // 0..3
    const int wcol = w * 64;

    f32x4 acc[8][4];
#pragma unroll
    for (int m = 0; m < 8; m++)
#pragma unroll
        for (int n = 0; n < 4; n++) acc[m][n] = (f32x4){0.f, 0.f, 0.f, 0.f};

    const int frowA = tid >> 1;                // A fill: 128 rows, 2 thr/row
    const int fqA   = tid & 1;                 // 16-short half
    const int frowB = tid >> 2;                // B fill: 64 rows/sweep, 4 thr/row
    const int fqB   = tid & 3;                 // 8-short quarter
    int fnode = base + frowA; if (fnode >= NN) fnode = 0;

    for (int k0 = 0; k0 < K; k0 += 32) {
        __syncthreads();
        {
            const ushort* srcp = (k0 < KH)
                ? agg + (size_t)fnode * KH + k0 + fqA * 16
                : xin + (size_t)fnode * KH + (k0 - KH) + fqA * 16;
            u32x4 a0 = *(const u32x4*)srcp;
            u32x4 a1 = *(const u32x4*)(srcp + 8);
            *(u32x4*)(&As[frowA * LDP + fqA * 16])     = a0;
            *(u32x4*)(&As[frowA * LDP + fqA * 16 + 8]) = a1;
        }
#pragma unroll
        for (int s = 0; s < 4; s++) {
            int c = frowB + s * 64;
            *(u32x4*)(&Bs[c * LDP + fqB * 8]) =
                *(const u32x4*)(Wt + (size_t)c * K + k0 + fqB * 8);
        }
        __syncthreads();

        short8 av[8], bv[4];
#pragma unroll
        for (int m = 0; m < 8; m++)
            av[m] = *(const short8*)(&As[(m * 16 + r) * LDP + kh * 8]);
#pragma unroll
        for (int n = 0; n < 4; n++)
            bv[n] = *(const short8*)(&Bs[(wcol + n * 16 + r) * LDP + kh * 8]);
#pragma unroll
        for (int m = 0; m < 8; m++)
#pragma unroll
            for (int n = 0; n < 4; n++)
                acc[m][n] = __builtin_amdgcn_mfma_f32_16x16x32_bf16(
                    av[m], bv[n], acc[m][n], 0, 0, 0);
    }

    float bj[4];
#pragma unroll
    for (int n = 0; n < 4; n++) bj[n] = bias[wcol + n * 16 + r];

#pragma unroll
    for (int m = 0; m < 8; m++) {
        int rowbase = base + m * 16 + (lane >> 4) * 4;
#pragma unroll
        for (int reg = 0; reg < 4; reg++) {
            int nd = rowbase + reg;
            if (nd < NN) {
#pragma unroll
                for (int n = 0; n < 4; n++) {
                    float v = acc[m][n][reg] + bj[n];
                    v = v > 0.0f ? v : 0.0f;
                    outb[(size_t)nd * HH + wcol + n * 16 + r] = f2b(v);
                    if (out8) out8[(size_t)nd * HH + wcol + n * 16 + r] = ftof8(v);
                }
            }
        }
    }
}

// ---------------- global mean pool (bf16 input, batch SORTED) ----------------
__global__ void k_pool(const ushort* __restrict__ h, const int* __restrict__ batch,
                       float* __restrict__ gpool) {
    __shared__ int sb[32];
    int j = threadIdx.x;
    int base = blockIdx.x * 32;
    int n = NN - base; if (n > 32) n = 32;
    if (j < n) sb[j] = batch[base + j];
    __syncthreads();
    float acc = 0.0f;
    int cur = sb[0];
    for (int t = 0; t < n; t++) {
        int g = sb[t];
        if (g != cur) {
            atomicAdd(&gpool[cur * HH + j], acc);
            acc = 0.0f;
            cur = g;
        }
        acc += b2f_lo((uint)h[(size_t)(base + t) * HH + j]);
    }
    atomicAdd(&gpool[cur * HH + j], acc);
}

// ---------------- heads (f32): one block per graph ----------------
__global__ void k_head(const float* __restrict__ gpool, const float* __restrict__ gcnt,
                       const float* __restrict__ Wa1, const float* __restrict__ ba1,
                       const float* __restrict__ Wa2, const float* __restrict__ ba2,
                       const float* __restrict__ Wc1, const float* __restrict__ bc1,
                       const float* __restrict__ Wc2, const float* __restrict__ bc2,
                       float* __restrict__ outp) {
    __shared__ float gv[HH], ha[HH], hc[HH];
    int g = blockIdx.x, j = threadIdx.x;
    float c = gcnt[g];
    c = c > 1.0f ? c : 1.0f;
    gv[j] = gpool[g * HH + j] * __builtin_amdgcn_rcpf(c);
    __syncthreads();
    float a_acc = ba1[j], c_acc = bc1[j];
#pragma unroll 2
    for (int k = 0; k < HH; k += 4) {
        float4 g4 = *reinterpret_cast<const float4*>(&gv[k]);
        const float* WA = Wa1 + k * HH + j;
        const float* WC = Wc1 + k * HH + j;
        a_acc += g4.x * WA[0] + g4.y * WA[HH] + g4.z * WA[2 * HH] + g4.w * WA[3 * HH];
        c_acc += g4.x * WC[0] + g4.y * WC[HH] + g4.z * WC[2 * HH] + g4.w * WC[3 * HH];
    }
    ha[j] = a_acc > 0.0f ? a_acc : 0.0f;
    hc[j] = c_acc > 0.0f ? c_acc : 0.0f;
    __syncthreads();
    if (j < AA) {
        float m = ba2[j];
        for (int k = 0; k < HH; k++) m += ha[k] * Wa2[k * AA + j];
        outp[g * AA + j] = m;
    } else if (j == AA) {
        float v = bc2[0];
        for (int k = 0; k < HH; k++) v += hc[k] * Wc2[k];
        outp[GG * AA + g] = v;
    }
}

extern "C" void kernel_launch(void* const* d_in, const int* in_sizes, int n_in,
                              void* d_out, int out_size, void* d_ws, size_t ws_size,
                              hipStream_t stream) {
    const float* x     = (const float*)d_in[0];
    const int*   ei    = (const int*)d_in[1];
    const int*   batch = (const int*)d_in[2];
    const float* Wl1 = (const float*)d_in[3];
    const float* bl1 = (const float*)d_in[4];
    const float* Wr1 = (const float*)d_in[5];
    const float* Wl2 = (const float*)d_in[6];
    const float* bl2 = (const float*)d_in[7];
    const float* Wr2 = (const float*)d_in[8];
    const float* Wa1 = (const float*)d_in[9];
    const float* ba1 = (const float*)d_in[10];
    const float* Wa2 = (const float*)d_in[11];
    const float* ba2 = (const float*)d_in[12];
    const float* Wc1 = (const float*)d_in[13];
    const float* bc1 = (const float*)d_in[14];
    const float* Wc2 = (const float*)d_in[15];
    const float* bc2 = (const float*)d_in[16];
    float* out = (float*)d_out;

    const int* srcv = ei;
    const int* dstv = ei + NE;

    // workspace layout (bytes, 256-aligned), total ~103.5 MB
    char* ws = (char*)d_ws;
    int*    degi     = (int*)(ws + 0);           // 200192
    int*    offsets  = (int*)(ws + 200192);      // 200448
    int*    cursor   = (int*)(ws + 400640);      // 200192
    int*    blocksum = (int*)(ws + 600832);      // 1024
    int*    blockoff = (int*)(ws + 601856);      // 1024
    float*  gcnt     = (float*)(ws + 602880);    // 256
    float*  gpool    = (float*)(ws + 603136);    // 65536
    int*    csr_src  = (int*)(ws + 668672);      // 6400000
    ushort* xb       = (ushort*)(ws + 7068672);  // 12800000  x bf16
    ushort* agg1b    = (ushort*)(ws + 19868672); // 12800000
    ushort* h1b      = (ushort*)(ws + 32668672); // 25600000
    ushort* agg2b    = (ushort*)(ws + 58268672); // 25600000  (h2 in-place)
    ushort* Wt1      = (ushort*)(ws + 83868672); // 131072
    ushort* Wt2      = (ushort*)(ws + 83999744); // 262144
    unsigned char* xf8  = (unsigned char*)(ws + 84261888); // 6400000  x fp8
    unsigned char* h1f8 = (unsigned char*)(ws + 90661888); // 12800000 h1 fp8

    // merged casts + zero-init (degi, gcnt+gpool)
    k_prep<<<7279, 256, 0, stream>>>(x, xb, xf8, Wl1, Wr1, Wt1, Wl2, Wr2, Wt2,
                                     degi, gcnt);

    const int nch = (NE / 4 + 255) / 256;   // 1563 edge chunks (int4 granularity)
    k_degi<<<nch * NRANGE, 256, 0, stream>>>(dstv, degi);
    k_gdeg<<<(NN + 255) / 256, 256, 0, stream>>>(batch, gcnt);
    k_scan1<<<NB, 256, 0, stream>>>(degi, blocksum);
    k_scan2<<<1, 256, 0, stream>>>(blocksum, blockoff);
    k_scan3<<<NB, 256, 0, stream>>>(degi, blockoff, offsets, cursor);
    k_fill<<<nch * NRANGE, 256, 0, stream>>>(srcv, dstv, cursor, csr_src);

    // layer 1: XCD-sliced fp8 gather of x (2 slices x 4 XCDs), then MFMA GEMM
    {
        const int npb = ((NN / 2) + 15) / 16;          // 782 chunks per XCD
        k_gather_xcd<FIN><<<npb * 8, 256, 0, stream>>>(offsets, csr_src, xf8, agg1b);
    }
    k_sage_mfma<2 * FIN><<<(NN + 127) / 128, 256, 0, stream>>>(agg1b, xb, Wt1, bl1, h1b, h1f8);

    // layer 2: XCD-sliced fp8 gather of h1 (4 slices x 2 XCDs), then MFMA GEMM
    {
        const int npb = ((NN / 2) + 15) / 16;          // 1563 chunks per XCD
        k_gather_xcd<HH><<<npb * 8, 256, 0, stream>>>(offsets, csr_src, h1f8, agg2b);
    }
    k_sage_mfma<2 * HH><<<(NN + 127) / 128, 256, 0, stream>>>(agg2b, h1b, Wt2, bl2, agg2b, nullptr);

    // pool + heads
    k_pool<<<(NN + 31) / 32, 256, 0, stream>>>(agg2b, batch, gpool);
    k_head<<<GG, 256, 0, stream>>>(gpool, gcnt, Wa1, ba1, Wa2, ba2, Wc1, bc1, Wc2, bc2, out);
}

// Round 12
// 432.417 us; speedup vs baseline: 1.0762x; 1.0762x over previous
//
#include <hip/hip_runtime.h>
#include <hip/hip_bf16.h>
#include <hip/hip_fp8.h>

#define NN 50000
#define NE 1600000
#define FIN 128
#define HH 256
#define GG 64
#define AA 16
#define NB ((NN + 255) / 256)   // 196 scan blocks
#define NRANGE 8
#define RSZ (NN / NRANGE)        // 6250 dst nodes per XCD range

typedef __attribute__((ext_vector_type(8))) short short8;
typedef __attribute__((ext_vector_type(4))) float f32x4;
typedef __attribute__((ext_vector_type(4))) int   i32x4;   // native vec for nt builtins
typedef __attribute__((ext_vector_type(4))) uint  u32x4;

static __device__ __forceinline__ ushort f2b(float f) {
    union { __hip_bfloat16 h; ushort u; } v; v.h = __float2bfloat16(f); return v.u;
}
static __device__ __forceinline__ float b2f_lo(uint a) {
    union { float f; uint u; } v; v.u = a << 16; return v.f;
}
template<int SEL>
static __device__ __forceinline__ float f8tof(uint u) {
#if __has_builtin(__builtin_amdgcn_cvt_f32_fp8)
    return __builtin_amdgcn_cvt_f32_fp8(u, SEL);
#else
    union { unsigned char c; __hip_fp8_e4m3 f; } v;
    v.c = (u >> (SEL * 8)) & 0xFF;
    return (float)v.f;
#endif
}
static __device__ __forceinline__ unsigned char ftof8(float f) {
    __hip_fp8_e4m3 v(f);
    return *reinterpret_cast<unsigned char*>(&v);
}

// ---------------- merged prep: casts + zero-init ----------------
__global__ void k_prep(const float* __restrict__ x, ushort* __restrict__ xb,
                       unsigned char* __restrict__ xf8,
                       const float* __restrict__ Wl1, const float* __restrict__ Wr1,
                       ushort* __restrict__ Wt1,
                       const float* __restrict__ Wl2, const float* __restrict__ Wr2,
                       ushort* __restrict__ Wt2,
                       int* __restrict__ degi, float* __restrict__ gz) {
    int b = blockIdx.x, t = threadIdx.x;
    if (b < 6250) {
        int i = b * 256 + t;                               // exact: NN*FIN/4
        float4 v = reinterpret_cast<const float4*>(x)[i];
        ushort4 o; o.x = f2b(v.x); o.y = f2b(v.y); o.z = f2b(v.z); o.w = f2b(v.w);
        reinterpret_cast<ushort4*>(xb)[i] = o;
        uchar4 p; p.x = ftof8(v.x); p.y = ftof8(v.y); p.z = ftof8(v.z); p.w = ftof8(v.w);
        reinterpret_cast<uchar4*>(xf8)[i] = p;
    } else if (b < 6506) {
        int i = (b - 6250) * 256 + t;                      // exact: 256*256
        int n = i / 256, k = i % 256;
        float v = (k < 128) ? Wl1[k * HH + n] : Wr1[(k - 128) * HH + n];
        Wt1[i] = f2b(v);
    } else if (b < 7018) {
        int i = (b - 6506) * 256 + t;                      // exact: 256*512
        int n = i / 512, k = i % 512;
        float v = (k < 256) ? Wl2[k * HH + n] : Wr2[(k - 256) * HH + n];
        Wt2[i] = f2b(v);
    } else if (b < 7214) {
        int i = (b - 7018) * 256 + t;
        if (i < NN) degi[i] = 0;
    } else {
        int i = (b - 7214) * 256 + t;
        if (i < GG + GG * HH) gz[i] = 0.0f;
    }
}

// ---------------- degree histogram, XCD-partitioned, nt streaming reads ----------
__global__ void k_degi(const int* __restrict__ dst, int* __restrict__ degi) {
    int range = blockIdx.x & 7;
    int i = (blockIdx.x >> 3) * 256 + threadIdx.x;
    if (i >= NE / 4) return;
    i32x4 d = __builtin_nontemporal_load(reinterpret_cast<const i32x4*>(dst) + i);
    int lo = range * RSZ, hi = lo + RSZ;
    if (d.x >= lo && d.x < hi) atomicAdd(&degi[d.x], 1);
    if (d.y >= lo && d.y < hi) atomicAdd(&degi[d.y], 1);
    if (d.z >= lo && d.z < hi) atomicAdd(&degi[d.z], 1);
    if (d.w >= lo && d.w < hi) atomicAdd(&degi[d.w], 1);
}

__global__ void k_gdeg(const int* __restrict__ batch, float* __restrict__ gcnt) {
    __shared__ float h[GG];
    int t = threadIdx.x;
    if (t < GG) h[t] = 0.0f;
    __syncthreads();
    int i = blockIdx.x * 256 + t;
    if (i < NN) atomicAdd(&h[batch[i]], 1.0f);
    __syncthreads();
    if (t < GG && h[t] != 0.0f) atomicAdd(&gcnt[t], h[t]);
}

// ---------------- prefix sum over degrees ----------------
__global__ void k_scan1(const int* __restrict__ degi, int* __restrict__ blocksum) {
    __shared__ int s[256];
    int t = threadIdx.x, i = blockIdx.x * 256 + t;
    s[t] = i < NN ? degi[i] : 0;
    __syncthreads();
    for (int d = 128; d > 0; d >>= 1) { if (t < d) s[t] += s[t + d]; __syncthreads(); }
    if (t == 0) blocksum[blockIdx.x] = s[0];
}

__global__ void k_scan2(const int* __restrict__ blocksum, int* __restrict__ blockoff) {
    __shared__ int s[256];
    int t = threadIdx.x;
    int v = t < NB ? blocksum[t] : 0;
    s[t] = v; __syncthreads();
    for (int d = 1; d < 256; d <<= 1) {
        int x = t >= d ? s[t - d] : 0; __syncthreads();
        s[t] += x; __syncthreads();
    }
    if (t < NB) blockoff[t] = s[t] - v;
}

__global__ void k_scan3(const int* __restrict__ degi, const int* __restrict__ blockoff,
                        int* __restrict__ offsets, int* __restrict__ cursor) {
    __shared__ int s[256];
    int t = threadIdx.x, i = blockIdx.x * 256 + t;
    int v = i < NN ? degi[i] : 0;
    s[t] = v; __syncthreads();
    for (int d = 1; d < 256; d <<= 1) {
        int x = t >= d ? s[t - d] : 0; __syncthreads();
        s[t] += x; __syncthreads();
    }
    if (i < NN) {
        int off = blockoff[blockIdx.x] + s[t] - v;
        offsets[i] = off;
        cursor[i]  = off;
    }
    if (i == 0) offsets[NN] = NE;
}

// ---------------- CSR fill (ushort src), XCD-partitioned, nt reads ----------------
// src < 50000 fits ushort: halves scattered-store bytes (32 slots per 64B line).
__global__ void k_fill(const int* __restrict__ src, const int* __restrict__ dst,
                       int* __restrict__ cursor, ushort* __restrict__ csr16) {
    int range = blockIdx.x & 7;
    int i = (blockIdx.x >> 3) * 256 + threadIdx.x;
    if (i >= NE / 4) return;
    i32x4 d = __builtin_nontemporal_load(reinterpret_cast<const i32x4*>(dst) + i);
    i32x4 s = __builtin_nontemporal_load(reinterpret_cast<const i32x4*>(src) + i);
    int lo = range * RSZ, hi = lo + RSZ;
    if (d.x >= lo && d.x < hi) csr16[atomicAdd(&cursor[d.x], 1)] = (ushort)s.x;
    if (d.y >= lo && d.y < hi) csr16[atomicAdd(&cursor[d.y], 1)] = (ushort)s.y;
    if (d.z >= lo && d.z < hi) csr16[atomicAdd(&cursor[d.z], 1)] = (ushort)s.z;
    if (d.w >= lo && d.w < hi) csr16[atomicAdd(&cursor[d.w], 1)] = (ushort)s.w;
}

// ---------------- gather mean-aggregation from fp8 table, bf16 out ----------------
template<int C>
__global__ void __launch_bounds__(256) k_gatherf8(
        const int* __restrict__ offsets, const ushort* __restrict__ csr16,
        const unsigned char* __restrict__ feat, ushort* __restrict__ agg) {
    constexpr int V = C / 64;                  // fp8 bytes per lane: 2 or 4
    int wid = threadIdx.x >> 6, lane = threadIdx.x & 63;
    int node = blockIdx.x * 4 + wid;
    if (node >= NN) return;
    int o0 = offsets[node], o1 = offsets[node + 1];
    const unsigned char* fp = feat + lane * V;
    float acc[V];
#pragma unroll
    for (int i = 0; i < V; i++) acc[i] = 0.0f;

    int t = o0;
    for (; t + 3 < o1; t += 4) {
        int s0 = __builtin_nontemporal_load(csr16 + t);
        int s1 = __builtin_nontemporal_load(csr16 + t + 1);
        int s2 = __builtin_nontemporal_load(csr16 + t + 2);
        int s3 = __builtin_nontemporal_load(csr16 + t + 3);
        if constexpr (V == 2) {
            uint u0 = *(const ushort*)(fp + (size_t)s0 * C);
            uint u1 = *(const ushort*)(fp + (size_t)s1 * C);
            uint u2 = *(const ushort*)(fp + (size_t)s2 * C);
            uint u3 = *(const ushort*)(fp + (size_t)s3 * C);
            acc[0] += (f8tof<0>(u0) + f8tof<0>(u1)) + (f8tof<0>(u2) + f8tof<0>(u3));
            acc[1] += (f8tof<1>(u0) + f8tof<1>(u1)) + (f8tof<1>(u2) + f8tof<1>(u3));
        } else {
            uint u0 = *(const uint*)(fp + (size_t)s0 * C);
            uint u1 = *(const uint*)(fp + (size_t)s1 * C);
            uint u2 = *(const uint*)(fp + (size_t)s2 * C);
            uint u3 = *(const uint*)(fp + (size_t)s3 * C);
            acc[0] += (f8tof<0>(u0) + f8tof<0>(u1)) + (f8tof<0>(u2) + f8tof<0>(u3));
            acc[1] += (f8tof<1>(u0) + f8tof<1>(u1)) + (f8tof<1>(u2) + f8tof<1>(u3));
            acc[2] += (f8tof<2>(u0) + f8tof<2>(u1)) + (f8tof<2>(u2) + f8tof<2>(u3));
            acc[3] += (f8tof<3>(u0) + f8tof<3>(u1)) + (f8tof<3>(u2) + f8tof<3>(u3));
        }
    }
    for (; t < o1; ++t) {
        int s0 = __builtin_nontemporal_load(csr16 + t);
        if constexpr (V == 2) {
            uint u0 = *(const ushort*)(fp + (size_t)s0 * C);
            acc[0] += f8tof<0>(u0); acc[1] += f8tof<1>(u0);
        } else {
            uint u0 = *(const uint*)(fp + (size_t)s0 * C);
            acc[0] += f8tof<0>(u0); acc[1] += f8tof<1>(u0);
            acc[2] += f8tof<2>(u0); acc[3] += f8tof<3>(u0);
        }
    }

    int deg = o1 - o0;
    float r = __builtin_amdgcn_rcpf(deg > 1 ? (float)deg : 1.0f);
    if constexpr (V == 2) {
        uint o = (uint)f2b(acc[0] * r) | ((uint)f2b(acc[1] * r) << 16);
        *(uint*)(agg + (size_t)node * C + lane * 2) = o;
    } else {
        uint2 o;
        o.x = (uint)f2b(acc[0] * r) | ((uint)f2b(acc[1] * r) << 16);
        o.y = (uint)f2b(acc[2] * r) | ((uint)f2b(acc[3] * r) << 16);
        *(uint2*)(agg + (size_t)node * C + lane * 4) = o;
    }
}

// ---------------- SAGE layer via MFMA: 128 nodes x 256 cols per block ----------
template<int K>
__global__ void __launch_bounds__(256) k_sage_mfma(
        const ushort* __restrict__ agg, const ushort* __restrict__ xin,
        const ushort* __restrict__ Wt, const float* __restrict__ bias,
        ushort* __restrict__ outb, unsigned char* __restrict__ out8) {
    constexpr int KH = K / 2;
    constexpr int LDP = 40;                    // padded row stride (shorts)
    __shared__ ushort As[128 * LDP];           // 128 nodes x 32 k
    __shared__ ushort Bs[256 * LDP];           // 256 cols x 32 k

    const int tid  = threadIdx.x;
    const int lane = tid & 63;
    const int w    = tid >> 6;
    const int base = blockIdx.x * 128;
    const int r    = lane & 15;
    const int kh   = lane >> 4;                // 0..3
    const int wcol = w * 64;

    f32x4 acc[8][4];
#pragma unroll
    for (int m = 0; m < 8; m++)
#pragma unroll
        for (int n = 0; n < 4; n++) acc[m][n] = (f32x4){0.f, 0.f, 0.f, 0.f};

    const int frowA = tid >> 1;                // A fill: 128 rows, 2 thr/row
    const int fqA   = tid & 1;                 // 16-short half
    const int frowB = tid >> 2;                // B fill: 64 rows/sweep, 4 thr/row
    const int fqB   = tid & 3;                 // 8-short quarter
    int fnode = base + frowA; if (fnode >= NN) fnode = 0;

    for (int k0 = 0; k0 < K; k0 += 32) {
        __syncthreads();
        {
            const ushort* srcp = (k0 < KH)
                ? agg + (size_t)fnode * KH + k0 + fqA * 16
                : xin + (size_t)fnode * KH + (k0 - KH) + fqA * 16;
            u32x4 a0 = *(const u32x4*)srcp;
            u32x4 a1 = *(const u32x4*)(srcp + 8);
            *(u32x4*)(&As[frowA * LDP + fqA * 16])     = a0;
            *(u32x4*)(&As[frowA * LDP + fqA * 16 + 8]) = a1;
        }
#pragma unroll
        for (int s = 0; s < 4; s++) {
            int c = frowB + s * 64;
            *(u32x4*)(&Bs[c * LDP + fqB * 8]) =
                *(const u32x4*)(Wt + (size_t)c * K + k0 + fqB * 8);
        }
        __syncthreads();

        short8 av[8], bv[4];
#pragma unroll
        for (int m = 0; m < 8; m++)
            av[m] = *(const short8*)(&As[(m * 16 + r) * LDP + kh * 8]);
#pragma unroll
        for (int n = 0; n < 4; n++)
            bv[n] = *(const short8*)(&Bs[(wcol + n * 16 + r) * LDP + kh * 8]);
#pragma unroll
        for (int m = 0; m < 8; m++)
#pragma unroll
            for (int n = 0; n < 4; n++)
                acc[m][n] = __builtin_amdgcn_mfma_f32_16x16x32_bf16(
                    av[m], bv[n], acc[m][n], 0, 0, 0);
    }

    float bj[4];
#pragma unroll
    for (int n = 0; n < 4; n++) bj[n] = bias[wcol + n * 16 + r];

#pragma unroll
    for (int m = 0; m < 8; m++) {
        int rowbase = base + m * 16 + (lane >> 4) * 4;
#pragma unroll
        for (int reg = 0; reg < 4; reg++) {
            int nd = rowbase + reg;
            if (nd < NN) {
#pragma unroll
                for (int n = 0; n < 4; n++) {
                    float v = acc[m][n][reg] + bj[n];
                    v = v > 0.0f ? v : 0.0f;
                    outb[(size_t)nd * HH + wcol + n * 16 + r] = f2b(v);
                    if (out8) out8[(size_t)nd * HH + wcol + n * 16 + r] = ftof8(v);
                }
            }
        }
    }
}

// ---------------- global mean pool (bf16 input, batch SORTED) ----------------
__global__ void k_pool(const ushort* __restrict__ h, const int* __restrict__ batch,
                       float* __restrict__ gpool) {
    __shared__ int sb[32];
    int j = threadIdx.x;
    int base = blockIdx.x * 32;
    int n = NN - base; if (n > 32) n = 32;
    if (j < n) sb[j] = batch[base + j];
    __syncthreads();
    float acc = 0.0f;
    int cur = sb[0];
    for (int t = 0; t < n; t++) {
        int g = sb[t];
        if (g != cur) {
            atomicAdd(&gpool[cur * HH + j], acc);
            acc = 0.0f;
            cur = g;
        }
        acc += b2f_lo((uint)h[(size_t)(base + t) * HH + j]);
    }
    atomicAdd(&gpool[cur * HH + j], acc);
}

// ---------------- heads (f32): one block per graph ----------------
__global__ void k_head(const float* __restrict__ gpool, const float* __restrict__ gcnt,
                       const float* __restrict__ Wa1, const float* __restrict__ ba1,
                       const float* __restrict__ Wa2, const float* __restrict__ ba2,
                       const float* __restrict__ Wc1, const float* __restrict__ bc1,
                       const float* __restrict__ Wc2, const float* __restrict__ bc2,
                       float* __restrict__ outp) {
    __shared__ float gv[HH], ha[HH], hc[HH];
    int g = blockIdx.x, j = threadIdx.x;
    float c = gcnt[g];
    c = c > 1.0f ? c : 1.0f;
    gv[j] = gpool[g * HH + j] * __builtin_amdgcn_rcpf(c);
    __syncthreads();
    float a_acc = ba1[j], c_acc = bc1[j];
#pragma unroll 2
    for (int k = 0; k < HH; k += 4) {
        float4 g4 = *reinterpret_cast<const float4*>(&gv[k]);
        const float* WA = Wa1 + k * HH + j;
        const float* WC = Wc1 + k * HH + j;
        a_acc += g4.x * WA[0] + g4.y * WA[HH] + g4.z * WA[2 * HH] + g4.w * WA[3 * HH];
        c_acc += g4.x * WC[0] + g4.y * WC[HH] + g4.z * WC[2 * HH] + g4.w * WC[3 * HH];
    }
    ha[j] = a_acc > 0.0f ? a_acc : 0.0f;
    hc[j] = c_acc > 0.0f ? c_acc : 0.0f;
    __syncthreads();
    if (j < AA) {
        float m = ba2[j];
        for (int k = 0; k < HH; k++) m += ha[k] * Wa2[k * AA + j];
        outp[g * AA + j] = m;
    } else if (j == AA) {
        float v = bc2[0];
        for (int k = 0; k < HH; k++) v += hc[k] * Wc2[k];
        outp[GG * AA + g] = v;
    }
}

extern "C" void kernel_launch(void* const* d_in, const int* in_sizes, int n_in,
                              void* d_out, int out_size, void* d_ws, size_t ws_size,
                              hipStream_t stream) {
    const float* x     = (const float*)d_in[0];
    const int*   ei    = (const int*)d_in[1];
    const int*   batch = (const int*)d_in[2];
    const float* Wl1 = (const float*)d_in[3];
    const float* bl1 = (const float*)d_in[4];
    const float* Wr1 = (const float*)d_in[5];
    const float* Wl2 = (const float*)d_in[6];
    const float* bl2 = (const float*)d_in[7];
    const float* Wr2 = (const float*)d_in[8];
    const float* Wa1 = (const float*)d_in[9];
    const float* ba1 = (const float*)d_in[10];
    const float* Wa2 = (const float*)d_in[11];
    const float* ba2 = (const float*)d_in[12];
    const float* Wc1 = (const float*)d_in[13];
    const float* bc1 = (const float*)d_in[14];
    const float* Wc2 = (const float*)d_in[15];
    const float* bc2 = (const float*)d_in[16];
    float* out = (float*)d_out;

    const int* srcv = ei;
    const int* dstv = ei + NE;

    // workspace layout (bytes, 256-aligned), total ~100 MB
    char* ws = (char*)d_ws;
    int*    degi     = (int*)(ws + 0);           // 200192
    int*    offsets  = (int*)(ws + 200192);      // 200448
    int*    cursor   = (int*)(ws + 400640);      // 200192
    int*    blocksum = (int*)(ws + 600832);      // 1024
    int*    blockoff = (int*)(ws + 601856);      // 1024
    float*  gcnt     = (float*)(ws + 602880);    // 256
    float*  gpool    = (float*)(ws + 603136);    // 65536
    ushort* csr16    = (ushort*)(ws + 668672);   // 3200000 (E ushort)
    ushort* xb       = (ushort*)(ws + 3868672);  // 12800000  x bf16
    ushort* agg1b    = (ushort*)(ws + 16668672); // 12800000
    ushort* h1b      = (ushort*)(ws + 29468672); // 25600000
    ushort* agg2b    = (ushort*)(ws + 55068672); // 25600000  (h2 in-place)
    ushort* Wt1      = (ushort*)(ws + 80668672); // 131072
    ushort* Wt2      = (ushort*)(ws + 80799744); // 262144
    unsigned char* xf8  = (unsigned char*)(ws + 81061888); // 6400000  x fp8
    unsigned char* h1f8 = (unsigned char*)(ws + 87461888); // 12800000 h1 fp8

    // merged casts + zero-init (degi, gcnt+gpool)
    k_prep<<<7279, 256, 0, stream>>>(x, xb, xf8, Wl1, Wr1, Wt1, Wl2, Wr2, Wt2,
                                     degi, gcnt);

    const int nch = (NE / 4 + 255) / 256;   // 1563 edge chunks (int4 granularity)
    k_degi<<<nch * NRANGE, 256, 0, stream>>>(dstv, degi);
    k_gdeg<<<(NN + 255) / 256, 256, 0, stream>>>(batch, gcnt);
    k_scan1<<<NB, 256, 0, stream>>>(degi, blocksum);
    k_scan2<<<1, 256, 0, stream>>>(blocksum, blockoff);
    k_scan3<<<NB, 256, 0, stream>>>(degi, blockoff, offsets, cursor);
    k_fill<<<nch * NRANGE, 256, 0, stream>>>(srcv, dstv, cursor, csr16);

    // layer 1: fp8 gather of x, then MFMA GEMM (writes h1 bf16 + fp8)
    k_gatherf8<FIN><<<(NN + 3) / 4, 256, 0, stream>>>(offsets, csr16, xf8, agg1b);
    k_sage_mfma<2 * FIN><<<(NN + 127) / 128, 256, 0, stream>>>(agg1b, xb, Wt1, bl1, h1b, h1f8);

    // layer 2: fp8 gather of h1, then MFMA GEMM (h2 overwrites agg2b in-place)
    k_gatherf8<HH><<<(NN + 3) / 4, 256, 0, stream>>>(offsets, csr16, h1f8, agg2b);
    k_sage_mfma<2 * HH><<<(NN + 127) / 128, 256, 0, stream>>>(agg2b, h1b, Wt2, bl2, agg2b, nullptr);

    // pool + heads
    k_pool<<<(NN + 31) / 32, 256, 0, stream>>>(agg2b, batch, gpool);
    k_head<<<GG, 256, 0, stream>>>(gpool, gcnt, Wa1, ba1, Wa2, ba2, Wc1, bc1, Wc2, bc2, out);
}